// Round 3
// baseline (3080.335 us; speedup 1.0000x reference)
//
#include <hip/hip_runtime.h>
#include <hip/hip_bf16.h>
#include <stdint.h>

// GRU: B=256, S=512, E=256, H=512, C=128
// 16 teams x 16 WGs. team tm = wg&15; member cu = wg>>4 owns h dims [32cu,32cu+32).
// Team covers batch rows [16tm,16tm+16). 4 waves/WG k-split fused K=768.
// h exchange: TAGGED 8B chunks {2 bf16 dims | u32 tag=t+1} stored sc0 sc1 (MALL).
// Tag rides with data atomically -> no ack, no flags: consumers poll-load the
// data itself and use it the moment tags match. Own slice bypasses MALL via LDS.

typedef __attribute__((ext_vector_type(8))) short bf16x8;
typedef __attribute__((ext_vector_type(4))) float f32x4;
typedef __attribute__((ext_vector_type(4))) unsigned u32x4;
typedef __attribute__((ext_vector_type(2))) unsigned u32x2;

#define SWZ(r) (((r)&7) << 4)

static __device__ __forceinline__ unsigned short f2bf(float f) {
  unsigned x = __builtin_bit_cast(unsigned, f);
  return (unsigned short)((x + 0x7fffu + ((x >> 16) & 1u)) >> 16);  // RNE
}
static __device__ __forceinline__ float bf2f(unsigned u) {
  return __builtin_bit_cast(float, u << 16);
}
static __device__ __forceinline__ void st_sys_u32(void* p, unsigned v) {
  asm volatile("global_store_dword %0, %1, off sc0 sc1" :: "v"(p), "v"(v) : "memory");
}
static __device__ __forceinline__ void st_sys_u64(void* p, unsigned lo, unsigned hi) {
  u32x2 v; v[0] = lo; v[1] = hi;
  asm volatile("global_store_dwordx2 %0, %1, off sc0 sc1" :: "v"(p), "v"(v) : "memory");
}

__global__ __launch_bounds__(256, 1) void gru_persistent(
    const float* __restrict__ x, const float* __restrict__ h0,
    const float* __restrict__ Wih, const float* __restrict__ Whh,
    const float* __restrict__ bih, const float* __restrict__ bhh,
    unsigned short* __restrict__ hbuf) {
  // per-row 1536B: [0,512) x_t bf16 swizzled; [512,1536) h bf16 swizzled.
  __shared__ __align__(16) char ldsb[16 * 1536];
  __shared__ __align__(16) float cb[4 * 4 * 2 * 256];  // [wave][type][nf][row*16+col]

  const int tid = threadIdx.x, wg = blockIdx.x;
  const int tm = wg & 15, cu = wg >> 4;
  const int wv = tid >> 6, ln = tid & 63;
  const int bm = tm << 4;
  const int d0 = cu << 5;

  // slot-major hbuf: slot s at s*512KB; team row = +tm*32768 + r*2048 (256x 8B chunks)
  char* slot0 = (char*)hbuf + (size_t)tm * 32768;
  char* slot1 = (char*)hbuf + 524288 + (size_t)tm * 32768;

  // ---- W slice -> VGPR bf16 B-frags (once) ----
  bf16x8 BF[3][2][6];
  {
    const int j = ln & 15, kg = ln >> 4;
#pragma unroll
    for (int g = 0; g < 3; ++g)
#pragma unroll
      for (int nf = 0; nf < 2; ++nf)
#pragma unroll
        for (int ks = 0; ks < 6; ++ks) {
          const int R = g * 512 + d0 + nf * 16 + j;
          const int k = 192 * wv + 32 * ks + 8 * kg;
          const float* src = (k < 256) ? Wih + (size_t)R * 256 + k
                                       : Whh + (size_t)R * 512 + (k - 256);
          bf16x8 v;
#pragma unroll
          for (int i = 0; i < 8; ++i) v[i] = (short)f2bf(src[i]);
          BF[g][nf][ks] = v;
        }
  }

  const int dl = tid & 15, rr = tid >> 4;
  const int dd0 = d0 + dl, dd1 = d0 + 16 + dl;
  const float bR0 = bih[dd0] + bhh[dd0], bR1 = bih[dd1] + bhh[dd1];
  const float bZ0 = bih[512 + dd0] + bhh[512 + dd0], bZ1 = bih[512 + dd1] + bhh[512 + dd1];
  const float bNx0 = bih[1024 + dd0], bNx1 = bih[1024 + dd1];
  const float bNh0 = bhh[1024 + dd0], bNh1 = bhh[1024 + dd1];

  float hr0 = h0[(size_t)(bm + rr) * 512 + dd0];
  float hr1 = h0[(size_t)(bm + rr) * 512 + dd1];

  // ---- init: tagged h0 -> slot0; clear own tag words in slot1 (cross-call alias
  //      fix: leftover tag 512 would collide at t=511); own slice -> LDS ----
  {
    unsigned a0 = f2bf(hr0), a1 = f2bf(hr1);
    unsigned p0 = __shfl_xor(a0, 1, 64), p1 = __shfl_xor(a1, 1, 64);
    if (!(dl & 1)) {
      unsigned pair0 = a0 | (p0 << 16), pair1 = a1 | (p1 << 16);
      char* rg = slot0 + rr * 2048;
      st_sys_u64(rg + 4 * (d0 + dl), pair0, 1u);
      st_sys_u64(rg + 4 * (d0 + 16 + dl), pair1, 1u);
      char* rc = slot1 + rr * 2048;
      st_sys_u32(rc + 4 * (d0 + dl) + 4, 0u);
      st_sys_u32(rc + 4 * (d0 + 16 + dl) + 4, 0u);
      char* rl = ldsb + rr * 1536;
      *(unsigned*)(rl + (512 + ((2 * (d0 + dl)) ^ SWZ(rr)))) = pair0;
      *(unsigned*)(rl + (512 + ((2 * (d0 + 16 + dl)) ^ SWZ(rr)))) = pair1;
    }
  }
  // one-time: clears+h0 drained so our later same-address slot1 writes can't pass them
  asm volatile("s_waitcnt vmcnt(0)" ::: "memory");

  // ---- x(0) prefetch: thread covers row tid>>4, floats [16*(tid&15), +16) ----
  const int xr = tid >> 4, xi = tid & 15;
  f32x4 xv[4];
  {
    const float* xb = x + ((size_t)(bm + xr) * 512 + 0) * 256 + xi * 16;
#pragma unroll
    for (int q = 0; q < 4; ++q) xv[q] = *(const f32x4*)(xb + 4 * q);
  }

  const int pr = rr, pi = dl;  // poll mapping: row pr, slice-owner pi (128B/thread)

  for (int t = 0; t < 512; ++t) {
    char* csl = (t & 1) ? slot1 : slot0;
    char* dsl = (t & 1) ? slot0 : slot1;

    u32x4 c0, c1, c2, c3, c4, c5, c6, c7;
    const char* prb = csl + pr * 2048 + pi * 128;

#define POLL_ISSUE()                                                                       \
  asm volatile("global_load_dwordx4 %0, %1, off sc0 sc1" : "=v"(c0) : "v"(prb) : "memory"); \
  asm volatile("global_load_dwordx4 %0, %1, off offset:16 sc0 sc1" : "=v"(c1) : "v"(prb) : "memory"); \
  asm volatile("global_load_dwordx4 %0, %1, off offset:32 sc0 sc1" : "=v"(c2) : "v"(prb) : "memory"); \
  asm volatile("global_load_dwordx4 %0, %1, off offset:48 sc0 sc1" : "=v"(c3) : "v"(prb) : "memory"); \
  asm volatile("global_load_dwordx4 %0, %1, off offset:64 sc0 sc1" : "=v"(c4) : "v"(prb) : "memory"); \
  asm volatile("global_load_dwordx4 %0, %1, off offset:80 sc0 sc1" : "=v"(c5) : "v"(prb) : "memory"); \
  asm volatile("global_load_dwordx4 %0, %1, off offset:96 sc0 sc1" : "=v"(c6) : "v"(prb) : "memory"); \
  asm volatile("global_load_dwordx4 %0, %1, off offset:112 sc0 sc1" : "=v"(c7) : "v"(prb) : "memory")

    if (pi != cu) { POLL_ISSUE(); }  // first round overlaps x-staging

    // ---- x(t) -> LDS bf16 (swizzled) ----
    {
      char* rowb = ldsb + xr * 1536;
      bf16x8 xa, xc;
#pragma unroll
      for (int q = 0; q < 4; ++q) {
        xa[q] = (short)f2bf(xv[0][q]); xa[4 + q] = (short)f2bf(xv[1][q]);
        xc[q] = (short)f2bf(xv[2][q]); xc[4 + q] = (short)f2bf(xv[3][q]);
      }
      *(bf16x8*)(rowb + ((32 * xi) ^ SWZ(xr))) = xa;
      *(bf16x8*)(rowb + ((32 * xi + 16) ^ SWZ(xr))) = xc;
    }

    if (pi != cu) {
      const unsigned tgt = (unsigned)(t + 1);
      while (true) {
        asm volatile("s_waitcnt vmcnt(0)"
                     : "+v"(c0), "+v"(c1), "+v"(c2), "+v"(c3),
                       "+v"(c4), "+v"(c5), "+v"(c6), "+v"(c7) :: "memory");
        unsigned bad = (c0[1] ^ tgt) | (c0[3] ^ tgt) | (c1[1] ^ tgt) | (c1[3] ^ tgt) |
                       (c2[1] ^ tgt) | (c2[3] ^ tgt) | (c3[1] ^ tgt) | (c3[3] ^ tgt) |
                       (c4[1] ^ tgt) | (c4[3] ^ tgt) | (c5[1] ^ tgt) | (c5[3] ^ tgt) |
                       (c6[1] ^ tgt) | (c6[3] ^ tgt) | (c7[1] ^ tgt) | (c7[3] ^ tgt);
        if (bad == 0) break;
        POLL_ISSUE();
      }
      // data already in hand: unpack to LDS h region (dims [32pi,32pi+32) of row pr)
      char* hl = ldsb + pr * 1536 + 512;
      const int ob = 64 * pi;
#define HWR(q, cc) { u32x2 vv; vv[0] = cc[0]; vv[1] = cc[2]; \
                     *(u32x2*)(hl + ((ob + 8 * q) ^ SWZ(pr))) = vv; }
      HWR(0, c0); HWR(1, c1); HWR(2, c2); HWR(3, c3);
      HWR(4, c4); HWR(5, c5); HWR(6, c6); HWR(7, c7);
#undef HWR
    }
    __syncthreads();  // B: all LDS staging done

    // ---- x(t+1) prefetch (plain loads, overlap MFMA) ----
    if (t + 1 < 512) {
      const float* xb2 = x + ((size_t)(bm + xr) * 512 + (t + 1)) * 256 + xi * 16;
#pragma unroll
      for (int q = 0; q < 4; ++q) xv[q] = *(const f32x4*)(xb2 + 4 * q);
    }

    // ---- MFMA over this wave's K range ----
    f32x4 aR[2] = {}, aZ[2] = {}, aNx[2] = {}, aNh[2] = {};
    {
      const int arow = ln & 15, kg = ln >> 4;
#pragma unroll
      for (int ks = 0; ks < 6; ++ks) {
        const int p = 384 * wv + 64 * ks + 16 * kg;
        bf16x8 a = *(const bf16x8*)(ldsb + arow * 1536 + (p ^ SWZ(arow)));
        const bool isx = (192 * wv + 32 * ks) < 256;
#pragma unroll
        for (int nf = 0; nf < 2; ++nf) {
          aR[nf] = __builtin_amdgcn_mfma_f32_16x16x32_bf16(a, BF[0][nf][ks], aR[nf], 0, 0, 0);
          aZ[nf] = __builtin_amdgcn_mfma_f32_16x16x32_bf16(a, BF[1][nf][ks], aZ[nf], 0, 0, 0);
          if (isx)
            aNx[nf] = __builtin_amdgcn_mfma_f32_16x16x32_bf16(a, BF[2][nf][ks], aNx[nf], 0, 0, 0);
          else
            aNh[nf] = __builtin_amdgcn_mfma_f32_16x16x32_bf16(a, BF[2][nf][ks], aNh[nf], 0, 0, 0);
        }
      }
    }

    // ---- partials -> cbuf ----
    {
      const int cc = ln & 15, cg = ln >> 4;
#pragma unroll
      for (int nf = 0; nf < 2; ++nf)
#pragma unroll
        for (int i = 0; i < 4; ++i) {
          const int row = cg * 4 + i;
          cb[((wv * 4 + 0) * 2 + nf) * 256 + row * 16 + cc] = aR[nf][i];
          cb[((wv * 4 + 1) * 2 + nf) * 256 + row * 16 + cc] = aZ[nf][i];
          if (wv <= 1) cb[((wv * 4 + 2) * 2 + nf) * 256 + row * 16 + cc] = aNx[nf][i];
          if (wv >= 1) cb[((wv * 4 + 3) * 2 + nf) * 256 + row * 16 + cc] = aNh[nf][i];
        }
    }
    __syncthreads();  // D

    // ---- combine + gates (fp32) ----
    {
#define CBX(w, ty, nf) cb[(((w) * 4 + (ty)) * 2 + (nf)) * 256 + rr * 16 + dl]
      float rp0 = bR0 + CBX(0,0,0) + CBX(1,0,0) + CBX(2,0,0) + CBX(3,0,0);
      float rp1 = bR1 + CBX(0,0,1) + CBX(1,0,1) + CBX(2,0,1) + CBX(3,0,1);
      float zp0 = bZ0 + CBX(0,1,0) + CBX(1,1,0) + CBX(2,1,0) + CBX(3,1,0);
      float zp1 = bZ1 + CBX(0,1,1) + CBX(1,1,1) + CBX(2,1,1) + CBX(3,1,1);
      float ix0 = bNx0 + CBX(0,2,0) + CBX(1,2,0);
      float ix1 = bNx1 + CBX(0,2,1) + CBX(1,2,1);
      float hn0 = bNh0 + CBX(1,3,0) + CBX(2,3,0) + CBX(3,3,0);
      float hn1 = bNh1 + CBX(1,3,1) + CBX(2,3,1) + CBX(3,3,1);
#undef CBX
      const float rg0 = 1.f / (1.f + __expf(-rp0)), rg1 = 1.f / (1.f + __expf(-rp1));
      const float zg0 = 1.f / (1.f + __expf(-zp0)), zg1 = 1.f / (1.f + __expf(-zp1));
      const float e0 = __expf(2.f * (ix0 + rg0 * hn0));
      const float e1 = __expf(2.f * (ix1 + rg1 * hn1));
      const float ng0 = 1.f - 2.f / (e0 + 1.f), ng1 = 1.f - 2.f / (e1 + 1.f);
      hr0 = ng0 + zg0 * (hr0 - ng0);
      hr1 = ng1 + zg1 * (hr1 - ng1);
    }

    // ---- pack h(t+1): tagged global (tag t+2) + own slice direct to LDS ----
    {
      unsigned a0 = f2bf(hr0), a1 = f2bf(hr1);
      unsigned p0 = __shfl_xor(a0, 1, 64), p1 = __shfl_xor(a1, 1, 64);
      if (!(dl & 1)) {
        unsigned pair0 = a0 | (p0 << 16), pair1 = a1 | (p1 << 16);
        const unsigned tg = (unsigned)(t + 2);
        char* rg = dsl + rr * 2048;
        st_sys_u64(rg + 4 * (d0 + dl), pair0, tg);
        st_sys_u64(rg + 4 * (d0 + 16 + dl), pair1, tg);
        char* rl = ldsb + rr * 1536;
        *(unsigned*)(rl + (512 + ((2 * (d0 + dl)) ^ SWZ(rr)))) = pair0;
        *(unsigned*)(rl + (512 + ((2 * (d0 + 16 + dl)) ^ SWZ(rr)))) = pair1;
      }
    }
    // no ack, no trailing barrier: tags carry the release; barrier B gates reuse
  }
#undef POLL_ISSUE
}

// ---- logits + masked CE + accuracy; one WG per batch row ----
__global__ __launch_bounds__(128) void logits_loss(
    const unsigned short* __restrict__ hbuf, const float* __restrict__ Wout,
    const float* __restrict__ bout, const int* __restrict__ label,
    float* __restrict__ accv) {
  __shared__ float hrow[512];
  __shared__ float lg[128];
  const int b = blockIdx.x;
  const int tm = b >> 4, r = b & 15;
  // h(512) lives in slot0, tagged-chunk layout: pair (2i,2i+1) at byte 8i
  const char* base = (const char*)hbuf + (size_t)tm * 32768 + r * 2048;
  for (int i = threadIdx.x; i < 256; i += 128) {
    const char* p = base + 8 * i;
    unsigned v;
    asm volatile("global_load_dword %0, %1, off sc0 sc1\n\ts_waitcnt vmcnt(0)"
                 : "=v"(v) : "v"(p) : "memory");
    hrow[2 * i] = bf2f(v & 0xffffu);
    hrow[2 * i + 1] = bf2f(v >> 16);
  }
  __syncthreads();
  const int c = threadIdx.x;
  const f32x4* w4 = (const f32x4*)(Wout + (size_t)c * 512);
  const f32x4* h4 = (const f32x4*)hrow;
  float s = bout[c];
#pragma unroll 4
  for (int i = 0; i < 128; ++i) {
    f32x4 wv = w4[i], hv = h4[i];
    s += wv[0] * hv[0] + wv[1] * hv[1] + wv[2] * hv[2] + wv[3] * hv[3];
  }
  lg[c] = s;
  __syncthreads();
  if (c == 0) {
    float mx = lg[0];
    int am = 0;
    for (int i = 1; i < 128; ++i)
      if (lg[i] > mx) { mx = lg[i]; am = i; }
    float se = 0.f;
    for (int i = 0; i < 128; ++i) se += __expf(lg[i] - mx);
    const int lb = label[b];
    const float logp = lg[lb] - mx - __logf(se);
    if (lb != 0) {
      atomicAdd(&accv[0], -logp);
      atomicAdd(&accv[1], 1.0f);
    }
    if (am == lb) atomicAdd(&accv[2], 1.0f);
  }
}

__global__ void finalize_k(const float* __restrict__ accv, float* __restrict__ out) {
  out[0] = accv[0] / fmaxf(accv[1], 1.0f);
  out[1] = accv[2] * (1.0f / 256.0f);
}

extern "C" void kernel_launch(void* const* d_in, const int* in_sizes, int n_in,
                              void* d_out, int out_size, void* d_ws, size_t ws_size,
                              hipStream_t stream) {
  (void)in_sizes; (void)n_in; (void)out_size; (void)ws_size;
  const float* x = (const float*)d_in[0];
  const int* label = (const int*)d_in[1];
  const float* h0 = (const float*)d_in[2];
  const float* Wih = (const float*)d_in[3];
  const float* Whh = (const float*)d_in[4];
  const float* bih = (const float*)d_in[5];
  const float* bhh = (const float*)d_in[6];
  const float* Wout = (const float*)d_in[7];
  const float* bout = (const float*)d_in[8];
  float* out = (float*)d_out;

  char* ws = (char*)d_ws;
  float* accv = (float*)ws;                              // 3 accumulators
  unsigned short* hbuf = (unsigned short*)(ws + 4096);   // 2 slots x 16 teams x 32KB

  hipMemsetAsync(ws, 0, 256, stream);  // accv only; tag hygiene handled in-kernel

  gru_persistent<<<dim3(256), dim3(256), 0, stream>>>(x, h0, Wih, Whh, bih, bhh, hbuf);
  logits_loss<<<dim3(256), dim3(128), 0, stream>>>(hbuf, Wout, bout, label, accv);
  finalize_k<<<dim3(1), dim3(1), 0, stream>>>(accv, out);
}